// Round 9
// baseline (102.775 us; speedup 1.0000x reference)
//
#include <hip/hip_runtime.h>

#define NNODES 10000
#define NEDGES 4096
#define INF 300
#define OUTF 150
#define EPB 8                       // edges per block (8 -> half the acc regs of 16)
#define NGROUPS (NEDGES / EPB)      // 512
#define SPLITK 5                    // K split over INF; 300/5 = 60
#define KCHUNK (INF / SPLITK)       // 60
#define PHASES 5                    // burst phases of 12 rows
#define PROWS (KCHUNK / PHASES)     // 12 (mult of 4 -> LDS float4 reads stay 16B-aligned)
#define ETHREADS 192                // lanes 0..149 compute

#define SUMS_N (NNODES * OUTF)      // 1,500,000
#define MSGS_N (NEDGES * OUTF)      //   614,400

// launch_bounds(192,6): VGPR cap 85; live set ~60 (16 acc + 24 burst + misc)
// -> no spill (R4 lesson) AND 6 waves/SIMD = 24 waves/CU residency.
// R6-R8 lesson: the kernel was occupancy-starved (5 blocks/CU, 4 waves/SIMD,
// ~40% occupancy); this round trades per-thread tile size for 2x residency.
__global__ __launch_bounds__(ETHREADS, 6) void edge_msg_kernel(
    const float* __restrict__ feat, const float* __restrict__ efeat,
    const float* __restrict__ W, const float* __restrict__ B,
    const int* __restrict__ src,
    float* __restrict__ part)
{
    __shared__ float hA[EPB][KCHUNK];   // gathered h chunk (1.92 KB)
    __shared__ float s_ef[EPB];
    __shared__ int   s_src[EPB];

    const int tid = threadIdx.x;
    const int kc  = blockIdx.x / NGROUPS;   // consecutive blocks share kc -> W rows L2-hot
    const int grp = blockIdx.x - kc * NGROUPS;
    const int e0  = grp * EPB;
    const int k0  = kc * KCHUNK;

    if (tid < EPB) {
        const int e = e0 + tid;
        s_src[tid] = src[e];
        s_ef[tid]  = efeat[e];
    }
    __syncthreads();

    // Stage h K-chunk for 8 edges: 8 rows x 15 float4 (16B-aligned).
    for (int q = tid; q < EPB * (KCHUNK / 4); q += ETHREADS) {
        const int el = q / (KCHUNK / 4);
        const int j4 = q - el * (KCHUNK / 4);
        *(float4*)&hA[el][4 * j4] =
            *(const float4*)(feat + (size_t)s_src[el] * INF + k0 + 4 * j4);
    }
    __syncthreads();

    if (tid < OUTF) {
        float accW[EPB], accB[EPB];     // dual acc: each h elem feeds 2 FMAs
        #pragma unroll
        for (int e = 0; e < EPB; ++e) { accW[e] = 0.f; accB[e] = 0.f; }

        const float* Wc = W + (size_t)k0 * OUTF + tid;  // column o = tid
        const float* Bc = B + (size_t)k0 * OUTF + tid;

        #pragma unroll
        for (int ph = 0; ph < PHASES; ++ph) {
            const int base = ph * PROWS;
            float wr[PROWS], br[PROWS];
            #pragma unroll
            for (int r = 0; r < PROWS; ++r) {
                wr[r] = Wc[(size_t)(base + r) * OUTF];   // 24 independent coalesced L2 loads
                br[r] = Bc[(size_t)(base + r) * OUTF];
            }
            // Pin: FMAs can't hoist above their burst; next phase's burst may
            // issue early within this region (natural pipelining).
            __builtin_amdgcn_sched_barrier(0);
            #pragma unroll
            for (int i4 = 0; i4 < PROWS; i4 += 4) {
                #pragma unroll
                for (int e = 0; e < EPB; ++e) {
                    const float4 h = *(const float4*)&hA[e][base + i4]; // broadcast, conflict-free
                    accW[e] = fmaf(h.w, wr[i4 + 3], fmaf(h.z, wr[i4 + 2],
                              fmaf(h.y, wr[i4 + 1], fmaf(h.x, wr[i4 + 0], accW[e]))));
                    accB[e] = fmaf(h.w, br[i4 + 3], fmaf(h.z, br[i4 + 2],
                              fmaf(h.y, br[i4 + 1], fmaf(h.x, br[i4 + 0], accB[e]))));
                }
            }
        }
        // Dense partial store (coalesced, no RMW): part[kc][e][o]
        float* pp = part + (size_t)kc * MSGS_N + (size_t)e0 * OUTF + tid;
        #pragma unroll
        for (int e = 0; e < EPB; ++e)
            pp[(size_t)e * OUTF] = fmaf(s_ef[e], accW[e], accB[e]);
    }
}

// Sum SPLITK partials per (e,o); ONE atomic per (e,o); counts here too.
__global__ __launch_bounds__(256) void reduce_scatter_kernel(
    const float* __restrict__ part, const int* __restrict__ dst,
    float* __restrict__ sums, float* __restrict__ cnts)
{
    const int idx = blockIdx.x * blockDim.x + threadIdx.x;
    if (idx < MSGS_N) {
        const int e = idx / OUTF;
        const int o = idx - e * OUTF;
        float s = 0.f;
        #pragma unroll
        for (int kc = 0; kc < SPLITK; ++kc)
            s += part[(size_t)kc * MSGS_N + idx];      // coalesced reads
        const int d = dst[e];
        atomicAdd(&sums[(size_t)d * OUTF + o], s);
        if (o == 0) atomicAdd(&cnts[d], 1.0f);         // each edge counted once
    }
}

__global__ __launch_bounds__(256) void finalize_kernel(
    const float* __restrict__ sums, const float* __restrict__ cnts,
    const float* __restrict__ bias, float* __restrict__ out)
{
    const int idx = blockIdx.x * blockDim.x + threadIdx.x;
    if (idx < SUMS_N) {
        const int n = idx / OUTF;
        const int o = idx - n * OUTF;
        const float c = cnts[n];
        const float m = sums[idx] / fmaxf(c, 1.0f);
        const float v = m + bias[o];
        out[idx] = v > 0.f ? v : 0.f;
    }
}

extern "C" void kernel_launch(void* const* d_in, const int* in_sizes, int n_in,
                              void* d_out, int out_size, void* d_ws, size_t ws_size,
                              hipStream_t stream) {
    const float* feat  = (const float*)d_in[0];
    const float* efeat = (const float*)d_in[1];
    const float* W     = (const float*)d_in[2];
    const float* B     = (const float*)d_in[3];
    const float* bias  = (const float*)d_in[4];
    const int*   src   = (const int*)d_in[5];
    const int*   dst   = (const int*)d_in[6];
    float* out  = (float*)d_out;

    float* sums = (float*)d_ws;                         // [SUMS_N]
    float* cnts = sums + SUMS_N;                        // [NNODES]
    float* part = cnts + NNODES;                        // [SPLITK * MSGS_N]

    // zero only sums+cnts (part is fully overwritten by edge_msg_kernel)
    hipMemsetAsync(d_ws, 0, (size_t)(SUMS_N + NNODES) * sizeof(float), stream);

    edge_msg_kernel<<<NGROUPS * SPLITK, ETHREADS, 0, stream>>>(
        feat, efeat, W, B, src, part);

    reduce_scatter_kernel<<<(MSGS_N + 255) / 256, 256, 0, stream>>>(
        part, dst, sums, cnts);

    finalize_kernel<<<(SUMS_N + 255) / 256, 256, 0, stream>>>(sums, cnts, bias, out);
}